// Round 3
// baseline (92.476 us; speedup 1.0000x reference)
//
#include <hip/hip_runtime.h>
#include <math.h>
#include <limits.h>

#define N_IMG 32
#define L_ROI 4096
#define M_GT  128
#define C_CLS 80
#define IOU_T 0.5f

// ---------------------------------------------------------------------------
// K1: per-roi IoU argmax vs all gt (LDS-staged) + unordered compaction of
//     positives into plist[n][*] = (roi_idx << 7) | label via wave-aggregated
//     atomics. Selection later is order-independent (min-index), so the
//     nondeterministic slot order does not affect the output.
// ---------------------------------------------------------------------------
__global__ __launch_bounds__(256) void k_match(
    const float4* __restrict__ rois,      // [N*L]
    const float4* __restrict__ gt_boxes,  // [N*M]
    const int*    __restrict__ gt_cls,    // [N*M]
    int* __restrict__ plist,              // [N*L] packed, unordered
    int* __restrict__ np_arr)             // [N] zeroed before launch
{
    __shared__ float4 sgt[M_GT];
    __shared__ float  sarea[M_GT];

    const int n    = blockIdx.x >> 4;          // 16 blocks per image
    const int lblk = (blockIdx.x & 15) * 256;
    const int t    = threadIdx.x;
    if (t < M_GT) {
        float4 g = gt_boxes[n * M_GT + t];
        sgt[t]   = g;
        sarea[t] = (g.z - g.x) * (g.w - g.y);
    }
    __syncthreads();

    const int l = lblk + t;
    float4 r = rois[(size_t)n * L_ROI + l];
    float ar = (r.z - r.x) * (r.w - r.y);

    float best = -1.0f;
    int   bi   = 0;
    #pragma unroll 4
    for (int m = 0; m < M_GT; ++m) {
        float4 g = sgt[m];
        float ix = fminf(r.z, g.z) - fmaxf(r.x, g.x);
        float iy = fminf(r.w, g.w) - fmaxf(r.y, g.y);
        ix = fmaxf(ix, 0.0f);
        iy = fmaxf(iy, 0.0f);
        float inter = ix * iy;
        float iou   = inter / (ar + sarea[m] - inter);
        if (iou > best) { best = iou; bi = m; }   // strict >: first-occurrence argmax
    }
    const int pos  = (best >= IOU_T) ? 1 : 0;
    const int lab  = gt_cls[n * M_GT + bi];
    const int lane = t & 63;

    unsigned long long mask = __ballot(pos);
    const int cnt = (int)__popcll(mask);
    if (cnt) {
        int wbase = 0;
        if (lane == 0) wbase = atomicAdd(&np_arr[n], cnt);
        wbase = __shfl(wbase, 0);
        if (pos) {
            int pref = (int)__popcll(mask & ((1ull << lane) - 1ull));
            plist[(size_t)n * L_ROI + wbase + pref] = (l << 7) | lab;
        }
    }
}

// ---------------------------------------------------------------------------
// K2: one wave per (image, class): select up to sn class-c positives in
//     increasing roi-index order (repeated min-reduce over the compact list),
//     compute each 80-class logsumexp wave-wide, accumulate nll.
//     Last block (ticket pattern) does the fixed-order final reduction.
// ---------------------------------------------------------------------------
__global__ __launch_bounds__(256) void k_selnll(
    const float* __restrict__ cls_scores,  // [N,L,C]
    const int*   __restrict__ plist,
    const int*   __restrict__ np_arr,
    float* __restrict__ nllsum,            // [N*C]
    int*   __restrict__ selcnt,            // [N*C]
    int*   __restrict__ done,              // [1] zeroed before launch
    float* __restrict__ out)
{
    const int wid  = (blockIdx.x << 2) + (threadIdx.x >> 6);   // N*C waves total
    const int n    = wid / C_CLS;
    const int c    = wid % C_CLS;
    const int lane = threadIdx.x & 63;

    const int np = np_arr[n];
    const int sn = max(1, (np + C_CLS - 1) / C_CLS);  // ceil(max(1, np/C))
    const int* pl = plist + (size_t)n * L_ROI;

    float lsum = 0.0f;
    int taken = 0, last = -1;
    while (taken < sn) {
        // min roi index > last among class-c entries
        int mymin = INT_MAX;
        for (int base = 0; base < np; base += 64) {
            const int e = (base + lane < np) ? pl[base + lane] : -1;
            if (e >= 0 && (e & 127) == c) {
                const int idx = e >> 7;
                if (idx > last) mymin = min(mymin, idx);
            }
        }
        #pragma unroll
        for (int o = 32; o; o >>= 1) mymin = min(mymin, __shfl_xor(mymin, o));
        if (mymin == INT_MAX) break;
        last = mymin;

        const float* rp = cls_scores + ((size_t)n * L_ROI + mymin) * C_CLS;
        float v0 = rp[lane];
        float v1 = (lane < C_CLS - 64) ? rp[64 + lane] : -INFINITY;
        float mx = fmaxf(v0, v1);
        #pragma unroll
        for (int o = 32; o; o >>= 1) mx = fmaxf(mx, __shfl_xor(mx, o));
        float s = expf(v0 - mx) + ((lane < C_CLS - 64) ? expf(v1 - mx) : 0.0f);
        #pragma unroll
        for (int o = 32; o; o >>= 1) s += __shfl_xor(s, o);
        const float logZ = mx + logf(s);
        const float sc = (c < 64) ? __shfl(v0, c) : __shfl(v1, c - 64);
        lsum += logZ - sc;
        ++taken;
    }
    if (lane == 0) { nllsum[wid] = lsum; selcnt[wid] = taken; }

    // ---- decoupled last-block final reduction ----
    __shared__ int amlast;
    __syncthreads();
    if (threadIdx.x == 0) {
        __threadfence();  // release our nllsum/selcnt writes
        int ticket = __hip_atomic_fetch_add(done, 1, __ATOMIC_ACQ_REL,
                                            __HIP_MEMORY_SCOPE_AGENT);
        amlast = (ticket == (int)gridDim.x - 1);
    }
    __syncthreads();
    if (amlast && threadIdx.x < 64) {
        __threadfence();  // acquire everyone's writes
        float tot = 0.0f;
        for (int i = 0; i < N_IMG; ++i) {
            float v = nllsum[i * C_CLS + lane] +
                      ((lane < C_CLS - 64) ? nllsum[i * C_CLS + 64 + lane] : 0.0f);
            int   q = selcnt[i * C_CLS + lane] +
                      ((lane < C_CLS - 64) ? selcnt[i * C_CLS + 64 + lane] : 0);
            #pragma unroll
            for (int o = 32; o; o >>= 1) {
                v += __shfl_xor(v, o);
                q += __shfl_xor(q, o);
            }
            tot += v / (float)q;
        }
        if (threadIdx.x == 0) out[0] = tot;
    }
}

extern "C" void kernel_launch(void* const* d_in, const int* in_sizes, int n_in,
                              void* d_out, int out_size, void* d_ws, size_t ws_size,
                              hipStream_t stream) {
    const float4* rois       = (const float4*)d_in[0];
    const float*  cls_scores = (const float*)d_in[1];
    // d_in[2] = bbox_deltas: only feeds 0.0 * chosen.sum() -> never read.
    const float4* gt_boxes   = (const float4*)d_in[3];
    const int*    gt_clses   = (const int*)d_in[4];
    float* out = (float*)d_out;

    char* ws = (char*)d_ws;
    int*   np_arr  = (int*)(ws + 0);        // 32 ints
    int*   done    = (int*)(ws + 128);      // 1 int
    float* nllsum  = (float*)(ws + 256);    // N*C floats (10240 B)
    int*   selcnt  = (int*)(ws + 10496);    // N*C ints   (10240 B)
    int*   plist   = (int*)(ws + 32768);    // N*L ints   (512 KiB)

    hipMemsetAsync(d_ws, 0, 256, stream);   // np_arr + done ticket

    k_match<<<N_IMG * (L_ROI / 256), 256, 0, stream>>>(
        rois, gt_boxes, gt_clses, plist, np_arr);
    k_selnll<<<(N_IMG * C_CLS) / 4, 256, 0, stream>>>(
        cls_scores, plist, np_arr, nllsum, selcnt, done, out);
}

// Round 5
// 87.692 us; speedup vs baseline: 1.0545x; 1.0545x over previous
//
#include <hip/hip_runtime.h>
#include <math.h>
#include <limits.h>

#define N_IMG 32
#define L_ROI 4096
#define M_GT  128
#define C_CLS 80
#define IOU_T 0.5f
#define NSEG  16          // L_ROI / 256 segments per image

// ---------------------------------------------------------------------------
// K1: per-roi IoU argmax vs all gt (LDS-staged). Each block owns one
//     256-roi segment and compacts its positives into plist[n][seg][*]
//     (roi order within segment) plus an unconditional count cnt[n][seg].
//     Block 0 also zeroes the ticket used by K2's last-block reduction
//     (stream order guarantees it lands before K2 starts — no memset node).
// ---------------------------------------------------------------------------
__global__ __launch_bounds__(256) void k_match(
    const float4* __restrict__ rois,      // [N*L]
    const float4* __restrict__ gt_boxes,  // [N*M]
    const int*    __restrict__ gt_cls,    // [N*M]
    int* __restrict__ plist,              // [N][NSEG][256] packed
    int* __restrict__ cnt,                // [N][NSEG]
    int* __restrict__ ticket)             // [1] -> 0
{
    __shared__ float4 sgt[M_GT];
    __shared__ float  sarea[M_GT];
    __shared__ int    swt[4];

    const int n   = blockIdx.x >> 4;
    const int seg = blockIdx.x & 15;
    const int t   = threadIdx.x;
    if (blockIdx.x == 0 && t == 0) *ticket = 0;
    if (t < M_GT) {
        float4 g = gt_boxes[n * M_GT + t];
        sgt[t]   = g;
        sarea[t] = (g.z - g.x) * (g.w - g.y);
    }
    __syncthreads();

    const int l = seg * 256 + t;
    float4 r = rois[(size_t)n * L_ROI + l];
    float ar = (r.z - r.x) * (r.w - r.y);

    float best = -1.0f;
    int   bi   = 0;
    #pragma unroll 4
    for (int m = 0; m < M_GT; ++m) {
        float4 g = sgt[m];
        float ix = fminf(r.z, g.z) - fmaxf(r.x, g.x);
        float iy = fminf(r.w, g.w) - fmaxf(r.y, g.y);
        ix = fmaxf(ix, 0.0f);
        iy = fmaxf(iy, 0.0f);
        float inter = ix * iy;
        float iou   = inter / (ar + sarea[m] - inter);
        if (iou > best) { best = iou; bi = m; }   // strict >: first-occurrence argmax
    }
    const int pos  = (best >= IOU_T) ? 1 : 0;
    const int lab  = gt_cls[n * M_GT + bi];
    const int lane = t & 63;
    const int wv   = t >> 6;

    unsigned long long mask = __ballot(pos);
    if (lane == 0) swt[wv] = (int)__popcll(mask);
    __syncthreads();
    int woff = 0;
    for (int w = 0; w < wv; ++w) woff += swt[w];
    if (pos) {
        int pref = (int)__popcll(mask & ((1ull << lane) - 1ull));
        plist[((n * NSEG + seg) << 8) + woff + pref] = (l << 7) | lab;
    }
    if (t == 0) cnt[n * NSEG + seg] = swt[0] + swt[1] + swt[2] + swt[3];
}

// ---------------------------------------------------------------------------
// K2: one wave per (image, class): select up to sn class-c positives in
//     increasing roi-index order (repeated min-reduce over segment lists),
//     wave-wide 80-class logsumexp per selected roi. True last-arriving
//     block (ticket zeroed by K1) does the fixed-order final reduction.
// ---------------------------------------------------------------------------
__global__ __launch_bounds__(256) void k_selnll(
    const float* __restrict__ cls_scores,  // [N,L,C]
    const int*   __restrict__ plist,
    const int*   __restrict__ cnt,
    float* __restrict__ nllsum,            // [N*C]
    int*   __restrict__ selcnt,            // [N*C]
    int*   __restrict__ ticket,            // [1] == 0 at kernel start
    float* __restrict__ out)
{
    const int wid  = (blockIdx.x << 2) + (threadIdx.x >> 6);   // N*C waves
    const int n    = wid / C_CLS;
    const int c    = wid % C_CLS;
    const int lane = threadIdx.x & 63;

    const int myc = (lane < NSEG) ? cnt[n * NSEG + lane] : 0;
    int np = myc;
    #pragma unroll
    for (int o = 32; o; o >>= 1) np += __shfl_xor(np, o);
    const int sn = max(1, (np + C_CLS - 1) / C_CLS);  // ceil(max(1, np/C))
    const int* pl = plist + ((size_t)n << 12);

    float lsum = 0.0f;
    int taken = 0, last = -1;
    while (taken < sn) {
        int mymin = INT_MAX;
        for (int seg = 0; seg < NSEG; ++seg) {
            const int sc = __shfl(myc, seg);
            for (int b = 0; b < sc; b += 64) {
                if (b + lane < sc) {
                    const int e = pl[(seg << 8) + b + lane];
                    if ((e & 127) == c) {
                        const int idx = e >> 7;
                        if (idx > last) mymin = min(mymin, idx);
                    }
                }
            }
        }
        #pragma unroll
        for (int o = 32; o; o >>= 1) mymin = min(mymin, __shfl_xor(mymin, o));
        if (mymin == INT_MAX) break;
        last = mymin;

        const float* rp = cls_scores + ((size_t)n * L_ROI + mymin) * C_CLS;
        float v0 = rp[lane];
        float v1 = (lane < C_CLS - 64) ? rp[64 + lane] : -INFINITY;
        float mx = fmaxf(v0, v1);
        #pragma unroll
        for (int o = 32; o; o >>= 1) mx = fmaxf(mx, __shfl_xor(mx, o));
        float s = expf(v0 - mx) + ((lane < C_CLS - 64) ? expf(v1 - mx) : 0.0f);
        #pragma unroll
        for (int o = 32; o; o >>= 1) s += __shfl_xor(s, o);
        const float logZ = mx + logf(s);
        const float sc = (c < 64) ? __shfl(v0, c) : __shfl(v1, c - 64);
        lsum += logZ - sc;
        ++taken;
    }
    if (lane == 0) { nllsum[wid] = lsum; selcnt[wid] = taken; }

    // ---- decoupled last-block final reduction (ticket starts at 0) ----
    __shared__ int amlast;
    __syncthreads();
    if (threadIdx.x == 0) {
        __threadfence();  // release nllsum/selcnt
        int tk = __hip_atomic_fetch_add(ticket, 1, __ATOMIC_ACQ_REL,
                                        __HIP_MEMORY_SCOPE_AGENT);
        amlast = (tk == (int)gridDim.x - 1);   // true last arrival
    }
    __syncthreads();
    if (amlast && threadIdx.x < 64) {
        __threadfence();  // acquire all blocks' writes
        float tot = 0.0f;
        for (int i = 0; i < N_IMG; ++i) {
            float v = nllsum[i * C_CLS + lane] +
                      ((lane < C_CLS - 64) ? nllsum[i * C_CLS + 64 + lane] : 0.0f);
            int   q = selcnt[i * C_CLS + lane] +
                      ((lane < C_CLS - 64) ? selcnt[i * C_CLS + 64 + lane] : 0);
            #pragma unroll
            for (int o = 32; o; o >>= 1) {
                v += __shfl_xor(v, o);
                q += __shfl_xor(q, o);
            }
            tot += v / (float)q;
        }
        if (threadIdx.x == 0) out[0] = tot;
    }
}

extern "C" void kernel_launch(void* const* d_in, const int* in_sizes, int n_in,
                              void* d_out, int out_size, void* d_ws, size_t ws_size,
                              hipStream_t stream) {
    const float4* rois       = (const float4*)d_in[0];
    const float*  cls_scores = (const float*)d_in[1];
    // d_in[2] = bbox_deltas: only feeds 0.0 * chosen.sum() -> never read.
    const float4* gt_boxes   = (const float4*)d_in[3];
    const int*    gt_clses   = (const int*)d_in[4];
    float* out = (float*)d_out;

    char* ws = (char*)d_ws;
    int*   ticket  = (int*)(ws + 0);        // 1 int, zeroed by k_match each call
    int*   cnt     = (int*)(ws + 128);      // N*NSEG ints (2 KiB)
    float* nllsum  = (float*)(ws + 4096);   // N*C floats (10240 B)
    int*   selcnt  = (int*)(ws + 16384);    // N*C ints   (10240 B)
    int*   plist   = (int*)(ws + 32768);    // N*L ints   (512 KiB)

    k_match<<<N_IMG * NSEG, 256, 0, stream>>>(
        rois, gt_boxes, gt_clses, plist, cnt, ticket);
    k_selnll<<<(N_IMG * C_CLS) / 4, 256, 0, stream>>>(
        cls_scores, plist, cnt, nllsum, selcnt, ticket, out);
}

// Round 6
// 47.858 us; speedup vs baseline: 1.9323x; 1.8323x over previous
//
#include <hip/hip_runtime.h>
#include <math.h>

#define N_IMG 32
#define L_ROI 4096
#define M_GT  128
#define C_CLS 80
#define IOU_T 0.5f
#define NSEG  16          // L_ROI / 256 segments per image

// ---------------------------------------------------------------------------
// K1: per-roi IoU argmax vs all gt (LDS-staged). Each block owns one
//     256-roi segment and compacts its positives (roi-ordered) into
//     plist[n][seg][*] plus an unconditional count cnt[n][seg].
//     No atomics, no pre-zeroing, deterministic.
// ---------------------------------------------------------------------------
__global__ __launch_bounds__(256) void k_match(
    const float4* __restrict__ rois,      // [N*L]
    const float4* __restrict__ gt_boxes,  // [N*M]
    const int*    __restrict__ gt_cls,    // [N*M]
    int* __restrict__ plist,              // [N][NSEG][256] packed (l<<7|lab)
    int* __restrict__ cnt)                // [N][NSEG]
{
    __shared__ float4 sgt[M_GT];
    __shared__ float  sarea[M_GT];
    __shared__ int    swt[4];

    const int n   = blockIdx.x >> 4;
    const int seg = blockIdx.x & 15;
    const int t   = threadIdx.x;
    if (t < M_GT) {
        float4 g = gt_boxes[n * M_GT + t];
        sgt[t]   = g;
        sarea[t] = (g.z - g.x) * (g.w - g.y);
    }
    __syncthreads();

    const int l = seg * 256 + t;
    float4 r = rois[(size_t)n * L_ROI + l];
    float ar = (r.z - r.x) * (r.w - r.y);

    float best = -1.0f;
    int   bi   = 0;
    #pragma unroll 4
    for (int m = 0; m < M_GT; ++m) {
        float4 g = sgt[m];
        float ix = fminf(r.z, g.z) - fmaxf(r.x, g.x);
        float iy = fminf(r.w, g.w) - fmaxf(r.y, g.y);
        ix = fmaxf(ix, 0.0f);
        iy = fmaxf(iy, 0.0f);
        float inter = ix * iy;
        float iou   = inter / (ar + sarea[m] - inter);
        if (iou > best) { best = iou; bi = m; }   // strict >: first-occurrence argmax
    }
    const int pos  = (best >= IOU_T) ? 1 : 0;
    const int lab  = gt_cls[n * M_GT + bi];
    const int lane = t & 63;
    const int wv   = t >> 6;

    unsigned long long mask = __ballot(pos);
    if (lane == 0) swt[wv] = (int)__popcll(mask);
    __syncthreads();
    int woff = 0;
    for (int w = 0; w < wv; ++w) woff += swt[w];
    if (pos) {
        int pref = (int)__popcll(mask & ((1ull << lane) - 1ull));
        plist[((n * NSEG + seg) << 8) + woff + pref] = (l << 7) | lab;
    }
    if (t == 0) cnt[n * NSEG + seg] = swt[0] + swt[1] + swt[2] + swt[3];
}

// ---------------------------------------------------------------------------
// K2: one wave per (image, class). Shuffle prefix-sum over the 16 segment
//     counts gives a virtually-contiguous roi-ordered positive list; wave
//     gathers 64 entries per batch, ballots for class c, takes the first
//     sn in bit order (== roi order), one wave-wide 80-class logsumexp per
//     taken roi. Unconditional slot writes — no atomics, no init.
// ---------------------------------------------------------------------------
__global__ __launch_bounds__(256) void k_selnll(
    const float* __restrict__ cls_scores,  // [N,L,C]
    const int*   __restrict__ plist,
    const int*   __restrict__ cnt,
    float* __restrict__ nllsum,            // [N*C]
    int*   __restrict__ selcnt)            // [N*C]
{
    const int wid  = (blockIdx.x << 2) + (threadIdx.x >> 6);   // N*C waves
    const int n    = wid / C_CLS;
    const int c    = wid % C_CLS;
    const int lane = threadIdx.x & 63;

    const int segcnt = (lane < NSEG) ? cnt[n * NSEG + lane] : 0;
    // inclusive prefix over lanes 0..15 (higher lanes unused)
    int incl = segcnt;
    #pragma unroll
    for (int o = 1; o < NSEG; o <<= 1) {
        int y = __shfl_up(incl, o);
        if (lane >= o) incl += y;
    }
    const int np = __shfl(incl, NSEG - 1);
    const int sn = max(1, (np + C_CLS - 1) / C_CLS);  // == ceil(max(1, np/C))
    const int* pl = plist + ((size_t)n << 12);

    float lsum = 0.0f;
    int taken = 0;
    for (int base = 0; base < np && taken < sn; base += 64) {
        const int g = base + lane;
        // locate (seg, slot) for global position g
        int seg = 0;
        #pragma unroll
        for (int s = 0; s < NSEG - 1; ++s)
            if (__shfl(incl, s) <= g) seg = s + 1;
        const int st = __shfl(incl, seg) - __shfl(segcnt, seg);
        const int e  = (g < np) ? pl[(seg << 8) + (g - st)] : -1;

        unsigned long long m = __ballot(e >= 0 && (e & 127) == c);
        while (m && taken < sn) {
            const int src = __ffsll(m) - 1;
            m &= m - 1;
            const int roi = __shfl(e, src) >> 7;

            const float* rp = cls_scores + ((size_t)n * L_ROI + roi) * C_CLS;
            float v0 = rp[lane];
            float v1 = (lane < C_CLS - 64) ? rp[64 + lane] : -INFINITY;
            float mx = fmaxf(v0, v1);
            #pragma unroll
            for (int o = 32; o; o >>= 1) mx = fmaxf(mx, __shfl_xor(mx, o));
            float s = expf(v0 - mx) + ((lane < C_CLS - 64) ? expf(v1 - mx) : 0.0f);
            #pragma unroll
            for (int o = 32; o; o >>= 1) s += __shfl_xor(s, o);
            const float logZ = mx + logf(s);
            const float sc = (c < 64) ? __shfl(v0, c) : __shfl(v1, c - 64);
            lsum += logZ - sc;
            ++taken;
        }
    }
    if (lane == 0) { nllsum[wid] = lsum; selcnt[wid] = taken; }
}

// ---------------------------------------------------------------------------
// K3: one wave: per-image mean over 80 class slots, summed over images.
//     Kernel boundary provides the grid-wide sync (no ticket atomics).
// ---------------------------------------------------------------------------
__global__ void k_final(const float* __restrict__ nllsum,
                        const int*   __restrict__ selcnt,
                        float* __restrict__ out)
{
    const int lane = threadIdx.x;   // 64 threads
    float tot = 0.0f;
    for (int i = 0; i < N_IMG; ++i) {
        float v = nllsum[i * C_CLS + lane] +
                  ((lane < C_CLS - 64) ? nllsum[i * C_CLS + 64 + lane] : 0.0f);
        int   q = selcnt[i * C_CLS + lane] +
                  ((lane < C_CLS - 64) ? selcnt[i * C_CLS + 64 + lane] : 0);
        #pragma unroll
        for (int o = 32; o; o >>= 1) { v += __shfl_xor(v, o); q += __shfl_xor(q, o); }
        tot += v / (float)q;
    }
    if (lane == 0) out[0] = tot;
}

extern "C" void kernel_launch(void* const* d_in, const int* in_sizes, int n_in,
                              void* d_out, int out_size, void* d_ws, size_t ws_size,
                              hipStream_t stream) {
    const float4* rois       = (const float4*)d_in[0];
    const float*  cls_scores = (const float*)d_in[1];
    // d_in[2] = bbox_deltas: only feeds 0.0 * chosen.sum() -> never read.
    const float4* gt_boxes   = (const float4*)d_in[3];
    const int*    gt_clses   = (const int*)d_in[4];
    float* out = (float*)d_out;

    char* ws = (char*)d_ws;
    int*   cnt     = (int*)(ws + 128);      // N*NSEG ints (2 KiB)
    float* nllsum  = (float*)(ws + 4096);   // N*C floats (10240 B)
    int*   selcnt  = (int*)(ws + 16384);    // N*C ints   (10240 B)
    int*   plist   = (int*)(ws + 32768);    // N*L ints   (512 KiB)

    k_match<<<N_IMG * NSEG, 256, 0, stream>>>(rois, gt_boxes, gt_clses, plist, cnt);
    k_selnll<<<(N_IMG * C_CLS) / 4, 256, 0, stream>>>(cls_scores, plist, cnt, nllsum, selcnt);
    k_final<<<1, 64, 0, stream>>>(nllsum, selcnt, out);
}